// Round 15
// baseline (48.984 us; speedup 1.0000x reference)
//
#include <hip/hip_runtime.h>
#include <hip/hip_bf16.h>

// MHSA window attention: B=64 windows, H=32 heads, N=256 tokens, D=16.
// PERSISTENT blocks: grid 512 x 512 threads (8 waves), 2 blocks/CU, ALL
// resident. Each block owns 4 consecutive heads (bh = 4*bid .. +3; spans two
// 128B lines/row -> odd heads are L2 hits). Per head, raw f32 K/V stream
// HBM->LDS via global_load_lds (issued ONE HEAD AHEAD, zero VGPR cost), then
// a short convert phase builds the bf16 fragment buffers.
// Compute (proven): wave w owns q-tile w; mfma_f32_32x32x16_bf16 (K=16==D);
// swapped QK^T -> softmax lane-local; P in registers (permlane32_swap);
// V^T row 16 = ones -> PV accumulator reg8 IS the softmax denominator;
// QK pipelined 1 kt ahead. No __launch_bounds__ (R12 lesson).

typedef short bf16x8 __attribute__((ext_vector_type(8)));
typedef float f32x16 __attribute__((ext_vector_type(16)));

__device__ __forceinline__ unsigned int pk2(float a, float b) {
  __hip_bfloat162 hh = __float22bfloat162_rn(float2{a, b});   // v_cvt_pk_bf16_f32
  unsigned int u; __builtin_memcpy(&u, &hh, 4); return u;
}

#if __has_builtin(__builtin_amdgcn_permlane32_swap)
typedef int i32x2_t __attribute__((ext_vector_type(2)));
__device__ __forceinline__ void swap_halves(unsigned x, unsigned y, unsigned& ox, unsigned& oy) {
  i32x2_t r = __builtin_amdgcn_permlane32_swap((int)x, (int)y, false, false);
  ox = (unsigned)r.x;
  oy = (unsigned)r.y;
}
#else
__device__ __forceinline__ void swap_halves(unsigned x, unsigned y, unsigned& ox, unsigned& oy) {
  const int hi = (threadIdx.x & 63) >> 5;
  unsigned tx = (unsigned)__shfl_xor((int)x, 32);
  unsigned ty = (unsigned)__shfl_xor((int)y, 32);
  ox = hi ? ty : x;
  oy = hi ? y : tx;
}
#endif

// 16B/lane direct HBM->LDS. lds_base must be wave-uniform; HW scatters
// lane i to lds_base + i*16B (CK-style addrspace casts via uintptr_t).
__device__ __forceinline__ void gload16(const float* g, float* lds_base, int lane) {
#if __has_builtin(__builtin_amdgcn_global_load_lds)
  const __attribute__((address_space(1))) unsigned int* gp =
      reinterpret_cast<const __attribute__((address_space(1))) unsigned int*>(
          reinterpret_cast<uintptr_t>(g));
  __attribute__((address_space(3))) unsigned int* lp =
      reinterpret_cast<__attribute__((address_space(3))) unsigned int*>(
          reinterpret_cast<uintptr_t>(lds_base));
  __builtin_amdgcn_global_load_lds(gp, lp, 16, 0, 0);
#else
  *(float4*)(lds_base + lane * 4) = *(const float4*)g;
#endif
}

__global__ void mhsa_kernel(const float* __restrict__ inp, const float* __restrict__ table,
                            float* __restrict__ out) {
  const int bid = blockIdx.x;
  const int t = threadIdx.x;
  const int l = t & 63;
  const int w = t >> 6;       // wave 0..7 -> q-tile w
  const int q32 = l & 31;     // MFMA col (q index)
  const int hi = l >> 5;      // half-wave
  const int bh0 = bid << 2;   // 4 consecutive heads per block

  __shared__ __align__(16) short KF[8][64][8];   // K fragment-order (bf16)
  __shared__ __align__(16) short VF[16][34][8];  // V^T frag-order; d=16 row = ones
  __shared__ float tbl[128];                     // bias column * log2(e)
  __shared__ __align__(16) float Kraw[4096];     // raw f32 K [256][16] (next head)
  __shared__ __align__(16) float Vraw[4096];     // raw f32 V [256][16]

  if (t < 256) {
    // ones rows (denominator trick): VF[kb][hv*17 + 16][j] = 1.0bf16 (never overwritten)
    const int kb = t >> 4, hv = (t >> 3) & 1, j = t & 7;
    VF[kb][hv * 17 + 16][j] = (short)0x3F80;
  }

  const int lrow = l >> 2, lc4 = l & 3;

  // stream head bh's K/V into the raw LDS buffer (4 x global_load_lds / thread)
  auto issue_raw = [&](int bh) {
    const int b = bh >> 5, h = bh & 31;
    const float* gb = inp + (size_t)b * 393216 + h * 16;
    #pragma unroll
    for (int j = 0; j < 2; ++j) {
      const int rb = w * 32 + j * 16;                       // 16 rows per issue
      const float* gr = gb + (size_t)(rb + lrow) * 1536 + lc4 * 4;
      gload16(gr + 512,  Kraw + rb * 16, l);
      gload16(gr + 1024, Vraw + rb * 16, l);
    }
  };

  float4 qa, qb; float tv;
  auto issue_qt = [&](int bh) {   // Q fragment + table column -> regs
    const int b = bh >> 5, h = bh & 31;
    const float* qp = inp + (size_t)b * 393216 + h * 16
                          + (size_t)(w * 32 + q32) * 1536 + hi * 8;
    qa = *(const float4*)qp;
    qb = *(const float4*)(qp + 4);
    tv = (t < 127) ? table[t * 32 + h] : 0.f;
  };

  // raw f32 -> bf16 fragment buffers (reads are linear: conflict-free)
  auto convert_frag = [&]() {
    const int row0 = t >> 2, c4 = t & 3;
    #pragma unroll
    for (int rr = 0; rr < 2; ++rr) {
      const int row = row0 + rr * 128;
      const float4 kv = *(const float4*)(Kraw + row * 16 + c4 * 4);
      const float4 vv = *(const float4*)(Vraw + row * 16 + c4 * 4);
      short* kdst = &KF[0][0][0] + (row >> 5) * 512 + ((c4 >> 1) * 32 + (row & 31)) * 8 + (c4 & 1) * 4;
      *(int2*)kdst = make_int2(pk2(kv.x, kv.y), pk2(kv.z, kv.w));
      unsigned v01 = pk2(vv.x, vv.y), v23 = pk2(vv.z, vv.w);
      short* vdst = &VF[0][0][0] + (row >> 4) * 272 + (((row >> 3) & 1) * 17 + c4 * 4) * 8 + (row & 7);
      vdst[0]  = (short)(v01 & 0xffff);
      vdst[8]  = (short)(v01 >> 16);
      vdst[16] = (short)(v23 & 0xffff);
      vdst[24] = (short)(v23 >> 16);
    }
    if (t < 127) tbl[t] = tv * 1.4426950408889634f;
  };

  const float scale2 = 0.17677669529663687f * 1.4426950408889634f;  // 32^-0.5 * log2e
  const f32x16 z16 = {0.f};
  const short* kfb = &KF[0][0][0] + l * 8;                       // linear: conflict-free
  const int vslot = hi * 17 + (q32 > 16 ? 16 : q32);             // d row (>=16 -> ones row)
  const short* vfb = &VF[0][0][0] + vslot * 8;
  const int qbase = w * 32;
  const int bb = (qbase >> 2) + (q32 >> 2) + 63 - hi;

  // softmax + PV body for one 32kv tile (kt), consuming S-tile `s`
  auto body = [&](int kt, const f32x16& s, f32x16& o) {
    unsigned wd[8];
    #pragma unroll
    for (int m = 0; m < 4; ++m) {
      const float bias = tbl[bb - kt * 8 - 2 * m];
      float e0 = __builtin_amdgcn_exp2f(fmaf(s[4 * m + 0], scale2, bias));
      float e1 = __builtin_amdgcn_exp2f(fmaf(s[4 * m + 1], scale2, bias));
      float e2 = __builtin_amdgcn_exp2f(fmaf(s[4 * m + 2], scale2, bias));
      float e3 = __builtin_amdgcn_exp2f(fmaf(s[4 * m + 3], scale2, bias));
      wd[2 * m]     = pk2(e0, e1);
      wd[2 * m + 1] = pk2(e2, e3);
    }
    unsigned f0, f1, f2, f3;
    bf16x8 pf0, pf1;
    swap_halves(wd[0], wd[2], f0, f2);
    swap_halves(wd[1], wd[3], f1, f3);
    { unsigned a4[4] = { f0, f1, f2, f3 }; __builtin_memcpy(&pf0, a4, 16); }
    swap_halves(wd[4], wd[6], f0, f2);
    swap_halves(wd[5], wd[7], f1, f3);
    { unsigned a4[4] = { f0, f1, f2, f3 }; __builtin_memcpy(&pf1, a4, 16); }
    bf16x8 v0 = *(const bf16x8*)(vfb + (kt * 2 + 0) * 272);
    bf16x8 v1 = *(const bf16x8*)(vfb + (kt * 2 + 1) * 272);
    o = __builtin_amdgcn_mfma_f32_32x32x16_bf16(v0, pf0, o, 0, 0, 0);
    o = __builtin_amdgcn_mfma_f32_32x32x16_bf16(v1, pf1, o, 0, 0, 0);
  };

  // ---- prologue: stream head 0 ----
  issue_raw(bh0);
  issue_qt(bh0);
  __syncthreads();             // raw0 + q/tv arrived (barrier drains vmcnt)

  #pragma unroll 1
  for (int i = 0; i < 4; ++i) {
    convert_frag();            // raw(i) -> fragment buffers, tbl write
    bf16x8 q8;
    { unsigned qw[4] = { pk2(qa.x, qa.y), pk2(qa.z, qa.w),
                         pk2(qb.x, qb.y), pk2(qb.z, qb.w) };
      __builtin_memcpy(&q8, qw, 16); }
    __syncthreads();           // fragments ready; raw(i) fully consumed

    if (i < 3) { issue_raw(bh0 + i + 1); issue_qt(bh0 + i + 1); }  // stream next head

    // compute head i (QK pipelined 1 kt ahead)
    f32x16 o = z16;
    {
      bf16x8 kf0 = *(const bf16x8*)kfb;
      f32x16 s = __builtin_amdgcn_mfma_f32_32x32x16_bf16(kf0, q8, z16, 0, 0, 0);
      #pragma unroll
      for (int kt = 0; kt < 7; ++kt) {
        bf16x8 kfn = *(const bf16x8*)(kfb + (kt + 1) * 512);
        f32x16 s_next = __builtin_amdgcn_mfma_f32_32x32x16_bf16(kfn, q8, z16, 0, 0, 0);
        body(kt, s, o);
        s = s_next;
      }
      body(7, s, o);
    }

    // denominator: C row16 = reg8 of hi=0 lanes; broadcast to both halves
    const int bh = bh0 + i;
    const int b = bh >> 5, h = bh & 31;
    const float inv = 1.0f / __shfl(o[8], q32);
    float* op = out + (size_t)(b * 256 + qbase + q32) * 512 + h * 16 + hi * 4;
    float4 r0 = { o[0] * inv, o[1] * inv, o[2] * inv, o[3] * inv };
    float4 r1 = { o[4] * inv, o[5] * inv, o[6] * inv, o[7] * inv };
    *(float4*)op = r0;
    *(float4*)(op + 8) = r1;

    if (i < 3) __syncthreads();  // fragments consumed; raw(i+1) has landed
  }
}

extern "C" void kernel_launch(void* const* d_in, const int* in_sizes, int n_in,
                              void* d_out, int out_size, void* d_ws, size_t ws_size,
                              hipStream_t stream) {
  (void)in_sizes; (void)n_in; (void)out_size; (void)d_ws; (void)ws_size;
  const float* inp = (const float*)d_in[0];
  const float* tbl = (const float*)d_in[1];
  float* out = (float*)d_out;
  hipLaunchKernelGGL(mhsa_kernel, dim3(512), dim3(512), 0, stream, inp, tbl, out);
}

// Round 16
// 39.171 us; speedup vs baseline: 1.2505x; 1.2505x over previous
//
#include <hip/hip_runtime.h>
#include <hip/hip_bf16.h>

// MHSA window attention: B=64 windows, H=32 heads, N=256 tokens, D=16.
// HALF-HEAD blocks for fine-grained phase interleaving: 4096 blocks x 256
// threads (4 waves); block = (head, half); wave w owns q-tile half*4+w.
// 16 residency generations -> load bursts of some blocks overlap compute of
// others (continuous HBM streaming instead of phase-aligned bursts).
// Twin blocks (both halves of a head) land 8 dispatch slots apart on the SAME
// XCD (head=(bid&7)*256+(bid>>4)) -> twin's K/V re-read is an L2 hit.
// Compute (proven): mfma_f32_32x32x16_bf16 (K=16==D); swapped QK^T -> softmax
// lane-local; P in registers (permlane32_swap); V^T row 16 = ones -> PV
// accumulator reg8 IS the denominator; QK pipelined 1 kt ahead. No
// __launch_bounds__ (R12 lesson: the hint capped residency).

typedef short bf16x8 __attribute__((ext_vector_type(8)));
typedef float f32x16 __attribute__((ext_vector_type(16)));

__device__ __forceinline__ unsigned int pk2(float a, float b) {
  __hip_bfloat162 hh = __float22bfloat162_rn(float2{a, b});   // v_cvt_pk_bf16_f32
  unsigned int u; __builtin_memcpy(&u, &hh, 4); return u;
}

#if __has_builtin(__builtin_amdgcn_permlane32_swap)
typedef int i32x2_t __attribute__((ext_vector_type(2)));
__device__ __forceinline__ void swap_halves(unsigned x, unsigned y, unsigned& ox, unsigned& oy) {
  i32x2_t r = __builtin_amdgcn_permlane32_swap((int)x, (int)y, false, false);
  ox = (unsigned)r.x;
  oy = (unsigned)r.y;
}
#else
__device__ __forceinline__ void swap_halves(unsigned x, unsigned y, unsigned& ox, unsigned& oy) {
  const int hi = (threadIdx.x & 63) >> 5;
  unsigned tx = (unsigned)__shfl_xor((int)x, 32);
  unsigned ty = (unsigned)__shfl_xor((int)y, 32);
  ox = hi ? ty : x;
  oy = hi ? y : tx;
}
#endif

__global__ void mhsa_kernel(const float* __restrict__ inp, const float* __restrict__ table,
                            float* __restrict__ out) {
  const int bid = blockIdx.x;
  const int bh = ((bid & 7) << 8) | (bid >> 4);   // head; twins + neighbors share XCD
  const int half = (bid >> 3) & 1;                // which 4 q-tiles
  const int b = bh >> 5, h = bh & 31;
  const int t = threadIdx.x;
  const int l = t & 63;
  const int w = t >> 6;       // wave 0..3
  const int q32 = l & 31;     // MFMA col (q index)
  const int hi = l >> 5;      // half-wave
  const int qtile = half * 4 + w;

  __shared__ __align__(16) short KF[8][64][8];   // K fragment-order: [kv-tile32][lane][8]
  __shared__ __align__(16) short VF[16][34][8];  // V^T frag-order; d=16 row = ones
  __shared__ float tbl[128];                     // bias column * log2(e)

  const float* gbase = inp + (size_t)b * (256 * 1536) + h * 16;
  const int row0 = t >> 2, c4 = t & 3;

  // ---- Issue all global loads up front (K/V rows 0..255, Q fragment) ----
  const float* p0 = gbase + (size_t)(row0      ) * 1536 + c4 * 4;
  const float* p1 = gbase + (size_t)(row0 +  64) * 1536 + c4 * 4;
  const float* p2 = gbase + (size_t)(row0 + 128) * 1536 + c4 * 4;
  const float* p3 = gbase + (size_t)(row0 + 192) * 1536 + c4 * 4;
  float4 ka = *(const float4*)(p0 + 512);
  float4 va = *(const float4*)(p0 + 1024);
  float4 kb_ = *(const float4*)(p1 + 512);
  float4 vb_ = *(const float4*)(p1 + 1024);
  float4 kc = *(const float4*)(p2 + 512);
  float4 vc = *(const float4*)(p2 + 1024);
  float4 kd = *(const float4*)(p3 + 512);
  float4 vd = *(const float4*)(p3 + 1024);
  const float* qp = gbase + (size_t)(qtile * 32 + q32) * 1536 + hi * 8;
  float4 qa = *(const float4*)qp;
  float4 qb = *(const float4*)(qp + 4);

  if (t < 127) tbl[t] = table[t * 32 + h] * 1.4426950408889634f;
  {
    // ones rows (denominator trick): VF[kb][hv*17 + 16][j] = 1.0bf16
    const int kb = t >> 4, hv = (t >> 3) & 1, j = t & 7;
    VF[kb][hv * 17 + 16][j] = (short)0x3F80;
  }

  auto stage = [&](int row, const float4& kv, const float4& vv) {
    short* kdst = &KF[0][0][0] + (row >> 5) * 512 + ((c4 >> 1) * 32 + (row & 31)) * 8 + (c4 & 1) * 4;
    *(int2*)kdst = make_int2(pk2(kv.x, kv.y), pk2(kv.z, kv.w));
    unsigned v01 = pk2(vv.x, vv.y), v23 = pk2(vv.z, vv.w);
    short* vdst = &VF[0][0][0] + (row >> 4) * 272 + (((row >> 3) & 1) * 17 + c4 * 4) * 8 + (row & 7);
    vdst[0]  = (short)(v01 & 0xffff);
    vdst[8]  = (short)(v01 >> 16);
    vdst[16] = (short)(v23 & 0xffff);
    vdst[24] = (short)(v23 >> 16);
  };
  stage(row0, ka, va);
  stage(row0 + 64, kb_, vb_);
  stage(row0 + 128, kc, vc);
  stage(row0 + 192, kd, vd);

  // Q -> bf16 B-frag for this wave's tile
  bf16x8 q8;
  { unsigned qw[4] = { pk2(qa.x, qa.y), pk2(qa.z, qa.w),
                       pk2(qb.x, qb.y), pk2(qb.z, qb.w) };
    __builtin_memcpy(&q8, qw, 16); }

  __syncthreads();

  const float scale2 = 0.17677669529663687f * 1.4426950408889634f;  // 32^-0.5 * log2e
  const f32x16 z16 = {0.f};
  const short* kfb = &KF[0][0][0] + l * 8;                       // linear: conflict-free
  const int vslot = hi * 17 + (q32 > 16 ? 16 : q32);             // d row (>=16 -> ones row)
  const short* vfb = &VF[0][0][0] + vslot * 8;
  const int qbase = qtile * 32;
  const int bb = (qbase >> 2) + (q32 >> 2) + 63 - hi;

  // softmax + PV body for one 32kv tile (kt), consuming S-tile `s`
  auto body = [&](int kt, const f32x16& s, f32x16& o) {
    unsigned wd[8];
    #pragma unroll
    for (int m = 0; m < 4; ++m) {
      const float bias = tbl[bb - kt * 8 - 2 * m];
      float e0 = __builtin_amdgcn_exp2f(fmaf(s[4 * m + 0], scale2, bias));
      float e1 = __builtin_amdgcn_exp2f(fmaf(s[4 * m + 1], scale2, bias));
      float e2 = __builtin_amdgcn_exp2f(fmaf(s[4 * m + 2], scale2, bias));
      float e3 = __builtin_amdgcn_exp2f(fmaf(s[4 * m + 3], scale2, bias));
      wd[2 * m]     = pk2(e0, e1);
      wd[2 * m + 1] = pk2(e2, e3);
    }
    unsigned f0, f1, f2, f3;
    bf16x8 pf0, pf1;
    swap_halves(wd[0], wd[2], f0, f2);
    swap_halves(wd[1], wd[3], f1, f3);
    { unsigned a4[4] = { f0, f1, f2, f3 }; __builtin_memcpy(&pf0, a4, 16); }
    swap_halves(wd[4], wd[6], f0, f2);
    swap_halves(wd[5], wd[7], f1, f3);
    { unsigned a4[4] = { f0, f1, f2, f3 }; __builtin_memcpy(&pf1, a4, 16); }
    bf16x8 v0 = *(const bf16x8*)(vfb + (kt * 2 + 0) * 272);
    bf16x8 v1 = *(const bf16x8*)(vfb + (kt * 2 + 1) * 272);
    o = __builtin_amdgcn_mfma_f32_32x32x16_bf16(v0, pf0, o, 0, 0, 0);
    o = __builtin_amdgcn_mfma_f32_32x32x16_bf16(v1, pf1, o, 0, 0, 0);
  };

  // QK software-pipelined one kt ahead
  f32x16 o = z16;
  {
    bf16x8 kf0 = *(const bf16x8*)kfb;
    f32x16 s = __builtin_amdgcn_mfma_f32_32x32x16_bf16(kf0, q8, z16, 0, 0, 0);
    #pragma unroll
    for (int kt = 0; kt < 7; ++kt) {
      bf16x8 kfn = *(const bf16x8*)(kfb + (kt + 1) * 512);
      f32x16 s_next = __builtin_amdgcn_mfma_f32_32x32x16_bf16(kfn, q8, z16, 0, 0, 0);
      body(kt, s, o);
      s = s_next;
    }
    body(7, s, o);
  }

  // denominator: C row16 = reg8 of hi=0 lanes; broadcast to both halves
  const float inv = 1.0f / __shfl(o[8], q32);
  float* op = out + (size_t)(b * 256 + qbase + q32) * 512 + h * 16 + hi * 4;
  float4 r0 = { o[0] * inv, o[1] * inv, o[2] * inv, o[3] * inv };
  float4 r1 = { o[4] * inv, o[5] * inv, o[6] * inv, o[7] * inv };
  *(float4*)op = r0;
  *(float4*)(op + 8) = r1;
}

extern "C" void kernel_launch(void* const* d_in, const int* in_sizes, int n_in,
                              void* d_out, int out_size, void* d_ws, size_t ws_size,
                              hipStream_t stream) {
  (void)in_sizes; (void)n_in; (void)out_size; (void)d_ws; (void)ws_size;
  const float* inp = (const float*)d_in[0];
  const float* tbl = (const float*)d_in[1];
  float* out = (float*)d_out;
  hipLaunchKernelGGL(mhsa_kernel, dim3(4096), dim3(256), 0, stream, inp, tbl, out);
}